// Round 1
// baseline (457.967 us; speedup 1.0000x reference)
//
#include <hip/hip_runtime.h>

// VcpAtt: q = Wq@src_emb + bq ; k = Wk@tgt_emb + bk ;
// scores = softmax_m(2*q.k - ||k||^2)  (||q||^2 cancels in softmax)
// out = [src (copy), src_corr = tgt @ scores^T]
//
// fp16 hi/lo split (3-pass MFMA) for fp32-grade accuracy on gfx950.

typedef _Float16 f16;
typedef __attribute__((ext_vector_type(8))) _Float16 f16x8;
typedef __attribute__((ext_vector_type(4))) float f32x4;

constexpr int B_ = 2, E_ = 512, N_ = 4096, M_ = 4096;
constexpr int NC_ = 1024;            // n-chunk for S materialization
constexpr float WSCALE = 64.0f;      // keep W lo-residuals out of f16 denormal range

__device__ __forceinline__ f32x4 mfma16(f16x8 a, f16x8 b, f32x4 c) {
  return __builtin_amdgcn_mfma_f32_16x16x32_f16(a, b, c, 0, 0, 0);
}

// ---- split W into f16 hi/lo (scaled by WSCALE) --------------------------
__global__ void k_split_w(const float* __restrict__ Wq, const float* __restrict__ Wk,
                          f16* __restrict__ WqH, f16* __restrict__ WqL,
                          f16* __restrict__ WkH, f16* __restrict__ WkL) {
  int i = blockIdx.x * 256 + threadIdx.x;      // grid covers E_*E_
  float a = Wq[i] * WSCALE;
  f16 ah = (f16)a; WqH[i] = ah; WqL[i] = (f16)(a - (float)ah);
  float b = Wk[i] * WSCALE;
  f16 bh = (f16)b; WkH[i] = bh; WkL[i] = (f16)(b - (float)bh);
}

// ---- transpose (E,N) fp32 -> (N,E) f16 hi/lo ----------------------------
__global__ void k_tsplit(const float* __restrict__ Xq, const float* __restrict__ Xk,
                         f16* __restrict__ XqH, f16* __restrict__ XqL,
                         f16* __restrict__ XkH, f16* __restrict__ XkL) {
  __shared__ float tile[64][65];
  const int b = blockIdx.z >> 1, which = blockIdx.z & 1;
  const float* X = (which ? Xk : Xq) + (size_t)b * E_ * N_;
  f16* H = (which ? XkH : XqH) + (size_t)b * N_ * E_;
  f16* L = (which ? XkL : XqL) + (size_t)b * N_ * E_;
  const int e0 = blockIdx.x * 64, n0 = blockIdx.y * 64;
  const int x = threadIdx.x, y = threadIdx.y;
#pragma unroll
  for (int j = 0; j < 16; ++j) {
    int e = y * 16 + j;
    tile[e][x] = X[(size_t)(e0 + e) * N_ + n0 + x];   // coalesced along n
  }
  __syncthreads();
#pragma unroll
  for (int j = 0; j < 16; ++j) {
    int nl = y * 16 + j;
    float v = tile[x][nl];
    f16 h = (f16)v;
    H[(size_t)(n0 + nl) * E_ + e0 + x] = h;           // coalesced along e
    L[(size_t)(n0 + nl) * E_ + e0 + x] = (f16)(v - (float)h);
  }
}

// ---- projection GEMM: O[n][f] = sum_e Xt[n][e]*W[f][e]*(1/WSCALE) + bias[f]
// 128x128 block tile, 4 waves (2x2), 4x4 16x16x32 frags per wave, 3-pass h/l.
__global__ __launch_bounds__(256) void k_proj(
    const f16* __restrict__ XqH, const f16* __restrict__ XqL,
    const f16* __restrict__ XkH, const f16* __restrict__ XkL,
    const f16* __restrict__ WqH, const f16* __restrict__ WqL,
    const f16* __restrict__ WkH, const f16* __restrict__ WkL,
    const float* __restrict__ bq, const float* __restrict__ bk,
    f16* __restrict__ QH, f16* __restrict__ QL,
    f16* __restrict__ KH, f16* __restrict__ KL) {
  const int b = blockIdx.z >> 1, kind = blockIdx.z & 1;
  const f16* AH = (kind ? XkH : XqH) + (size_t)b * N_ * E_;
  const f16* AL = (kind ? XkL : XqL) + (size_t)b * N_ * E_;
  const f16* BH = kind ? WkH : WqH;
  const f16* BL = kind ? WkL : WqL;
  const float* bias = kind ? bk : bq;
  f16* OH = (kind ? KH : QH) + (size_t)b * N_ * E_;
  f16* OL = (kind ? KL : QL) + (size_t)b * N_ * E_;
  const int n0 = blockIdx.x * 128, f0 = blockIdx.y * 128;
  const int lane = threadIdx.x & 63, w = threadIdx.x >> 6;
  const int wr = (w >> 1) * 64, wc = (w & 1) * 64;
  const int r15 = lane & 15, koff = (lane >> 4) * 8;

  f32x4 acc[4][4] = {};
  for (int e0 = 0; e0 < E_; e0 += 32) {
    f16x8 ah[4], al[4], bh[4], bl[4];
#pragma unroll
    for (int i = 0; i < 4; ++i) {
      size_t ra = (size_t)(n0 + wr + i * 16 + r15) * E_ + e0 + koff;
      size_t rb = (size_t)(f0 + wc + i * 16 + r15) * E_ + e0 + koff;
      ah[i] = *(const f16x8*)(AH + ra);
      al[i] = *(const f16x8*)(AL + ra);
      bh[i] = *(const f16x8*)(BH + rb);
      bl[i] = *(const f16x8*)(BL + rb);
    }
#pragma unroll
    for (int i = 0; i < 4; ++i)
#pragma unroll
      for (int j = 0; j < 4; ++j) {
        acc[i][j] = mfma16(ah[i], bh[j], acc[i][j]);
        acc[i][j] = mfma16(ah[i], bl[j], acc[i][j]);
        acc[i][j] = mfma16(al[i], bh[j], acc[i][j]);
      }
  }
  const int rowg = (lane >> 4) * 4;
#pragma unroll
  for (int j = 0; j < 4; ++j) {
    int f = f0 + wc + j * 16 + r15;            // C/D: col = lane&15
    float bv = bias[f];
#pragma unroll
    for (int i = 0; i < 4; ++i) {
#pragma unroll
      for (int r = 0; r < 4; ++r) {
        int n = n0 + wr + i * 16 + rowg + r;   // C/D: row = (lane>>4)*4 + r
        float q = acc[i][j][r] * (1.0f / WSCALE) + bv;
        f16 h = (f16)q;
        OH[(size_t)n * E_ + f] = h;
        OL[(size_t)n * E_ + f] = (f16)(q - (float)h);
      }
    }
  }
}

// ---- kk[b*M+m] = sum_f k^2 ----------------------------------------------
__global__ void k_kk(const f16* __restrict__ KH, const f16* __restrict__ KL,
                     float* __restrict__ kk) {
  int row = blockIdx.x * 4 + (threadIdx.x >> 6);   // b*M + m
  int lane = threadIdx.x & 63;
  f16x8 h8 = *(const f16x8*)(KH + (size_t)row * E_ + lane * 8);
  f16x8 l8 = *(const f16x8*)(KL + (size_t)row * E_ + lane * 8);
  float s = 0.f;
#pragma unroll
  for (int i = 0; i < 8; ++i) {
    float v = (float)h8[i] + (float)l8[i];
    s += v * v;
  }
#pragma unroll
  for (int o = 32; o; o >>= 1) s += __shfl_xor(s, o);
  if (lane == 0) kk[row] = s;
}

// ---- S GEMM (chunked): S[b][nl][m] = 2*sum_e q*k - kk[b*M+m] ------------
__global__ __launch_bounds__(256) void k_sgemm(
    const f16* __restrict__ QH, const f16* __restrict__ QL,
    const f16* __restrict__ KH, const f16* __restrict__ KL,
    const float* __restrict__ kk, float* __restrict__ S, int n_base) {
  const int b = blockIdx.z;
  const int n0 = blockIdx.x * 128, m0 = blockIdx.y * 128;
  const int lane = threadIdx.x & 63, w = threadIdx.x >> 6;
  const int wr = (w >> 1) * 64, wc = (w & 1) * 64;
  const int r15 = lane & 15, koff = (lane >> 4) * 8;
  const f16* AH = QH + ((size_t)b * N_ + n_base) * E_;
  const f16* AL = QL + ((size_t)b * N_ + n_base) * E_;
  const f16* BH = KH + (size_t)b * M_ * E_;
  const f16* BL = KL + (size_t)b * M_ * E_;

  f32x4 acc[4][4] = {};
  for (int e0 = 0; e0 < E_; e0 += 32) {
    f16x8 ah[4], al[4], bh[4], bl[4];
#pragma unroll
    for (int i = 0; i < 4; ++i) {
      size_t ra = (size_t)(n0 + wr + i * 16 + r15) * E_ + e0 + koff;
      size_t rb = (size_t)(m0 + wc + i * 16 + r15) * E_ + e0 + koff;
      ah[i] = *(const f16x8*)(AH + ra);
      al[i] = *(const f16x8*)(AL + ra);
      bh[i] = *(const f16x8*)(BH + rb);
      bl[i] = *(const f16x8*)(BL + rb);
    }
#pragma unroll
    for (int i = 0; i < 4; ++i)
#pragma unroll
      for (int j = 0; j < 4; ++j) {
        acc[i][j] = mfma16(ah[i], bh[j], acc[i][j]);
        acc[i][j] = mfma16(ah[i], bl[j], acc[i][j]);
        acc[i][j] = mfma16(al[i], bh[j], acc[i][j]);
      }
  }
  const int rowg = (lane >> 4) * 4;
#pragma unroll
  for (int j = 0; j < 4; ++j) {
    int m = m0 + wc + j * 16 + r15;
    float kv = kk[(size_t)b * M_ + m];
#pragma unroll
    for (int i = 0; i < 4; ++i)
#pragma unroll
      for (int r = 0; r < 4; ++r) {
        int nl = n0 + wr + i * 16 + rowg + r;
        S[((size_t)b * NC_ + nl) * M_ + m] = 2.0f * acc[i][j][r] - kv;
      }
  }
}

// ---- row softmax + PV (V = tgt rows, 3 dims) ----------------------------
__global__ __launch_bounds__(256) void k_softpv(const float* __restrict__ S,
                                                const float* __restrict__ tgt,
                                                float* __restrict__ out, int n_base) {
  const int row = blockIdx.x;                // b*NC_ + nloc
  const int b = row / NC_, nloc = row % NC_;
  const int n = n_base + nloc;
  const float* srow = S + (size_t)row * M_;
  const int t = threadIdx.x;
  float4 v[4];
  float mx = -3.0e38f;
#pragma unroll
  for (int k = 0; k < 4; ++k) {
    v[k] = *(const float4*)(srow + (size_t)(k * 256 + t) * 4);
    mx = fmaxf(mx, fmaxf(fmaxf(v[k].x, v[k].y), fmaxf(v[k].z, v[k].w)));
  }
#pragma unroll
  for (int o = 32; o; o >>= 1) mx = fmaxf(mx, __shfl_xor(mx, o));
  __shared__ float wred[4];
  __shared__ float facc[4][4];
  const int w = t >> 6, lane = t & 63;
  if (lane == 0) wred[w] = mx;
  __syncthreads();
  mx = fmaxf(fmaxf(wred[0], wred[1]), fmaxf(wred[2], wred[3]));
  const float* t0 = tgt + ((size_t)b * 3 + 0) * M_;
  const float* t1 = tgt + ((size_t)b * 3 + 1) * M_;
  const float* t2 = tgt + ((size_t)b * 3 + 2) * M_;
  float sum = 0, p0 = 0, p1 = 0, p2 = 0;
#pragma unroll
  for (int k = 0; k < 4; ++k) {
    int m = (k * 256 + t) * 4;
    float4 g0 = *(const float4*)(t0 + m);
    float4 g1 = *(const float4*)(t1 + m);
    float4 g2 = *(const float4*)(t2 + m);
    float4 sv = v[k];
    float e0 = __expf(sv.x - mx), e1 = __expf(sv.y - mx),
          e2 = __expf(sv.z - mx), e3 = __expf(sv.w - mx);
    sum += e0 + e1 + e2 + e3;
    p0 += e0 * g0.x + e1 * g0.y + e2 * g0.z + e3 * g0.w;
    p1 += e0 * g1.x + e1 * g1.y + e2 * g1.z + e3 * g1.w;
    p2 += e0 * g2.x + e1 * g2.y + e2 * g2.z + e3 * g2.w;
  }
#pragma unroll
  for (int o = 32; o; o >>= 1) {
    sum += __shfl_xor(sum, o);
    p0 += __shfl_xor(p0, o);
    p1 += __shfl_xor(p1, o);
    p2 += __shfl_xor(p2, o);
  }
  if (lane == 0) { facc[w][0] = sum; facc[w][1] = p0; facc[w][2] = p1; facc[w][3] = p2; }
  __syncthreads();
  if (t == 0) {
    float S0 = facc[0][0] + facc[1][0] + facc[2][0] + facc[3][0];
    float P0 = facc[0][1] + facc[1][1] + facc[2][1] + facc[3][1];
    float P1 = facc[0][2] + facc[1][2] + facc[2][2] + facc[3][2];
    float P2 = facc[0][3] + facc[1][3] + facc[2][3] + facc[3][3];
    float inv = 1.0f / S0;
    float* oc = out + (size_t)B_ * 3 * N_;
    oc[((size_t)b * 3 + 0) * N_ + n] = P0 * inv;
    oc[((size_t)b * 3 + 1) * N_ + n] = P1 * inv;
    oc[((size_t)b * 3 + 2) * N_ + n] = P2 * inv;
  }
}

// ---- src passthrough ----------------------------------------------------
__global__ void k_copy(const float* __restrict__ src, float* __restrict__ out) {
  int i = blockIdx.x * 256 + threadIdx.x;
  out[i] = src[i];
}

extern "C" void kernel_launch(void* const* d_in, const int* in_sizes, int n_in,
                              void* d_out, int out_size, void* d_ws, size_t ws_size,
                              hipStream_t stream) {
  const float* src_emb = (const float*)d_in[0];
  const float* tgt_emb = (const float*)d_in[1];
  const float* src     = (const float*)d_in[2];
  const float* tgt     = (const float*)d_in[3];
  const float* Wq      = (const float*)d_in[4];
  const float* bq      = (const float*)d_in[5];
  const float* Wk      = (const float*)d_in[6];
  const float* bk      = (const float*)d_in[7];
  float* out = (float*)d_out;

  // workspace layout (Xt region aliases Schunk: Xt dead after k_proj)
  constexpr size_t SZX = (size_t)B_ * N_ * E_;        // elements per f16 array
  constexpr size_t R0   = 4 * SZX * sizeof(f16);      // 33,554,432 == Schunk bytes
  constexpr size_t OFFW = R0;
  constexpr size_t OFFQ = OFFW + 4 * (size_t)E_ * E_ * sizeof(f16);
  constexpr size_t OFFK2 = OFFQ + 4 * SZX * sizeof(f16);
  constexpr size_t NEED = OFFK2 + (size_t)B_ * M_ * sizeof(float);
  if (ws_size < NEED) return;  // insufficient scratch; fail loudly via validation

  char* ws = (char*)d_ws;
  float* Schunk = (float*)(ws);
  f16* XqH = (f16*)(ws);
  f16* XqL = XqH + SZX;
  f16* XkH = XqL + SZX;
  f16* XkL = XkH + SZX;
  f16* WqH = (f16*)(ws + OFFW);
  f16* WqL = WqH + (size_t)E_ * E_;
  f16* WkH = WqL + (size_t)E_ * E_;
  f16* WkL = WkH + (size_t)E_ * E_;
  f16* QH = (f16*)(ws + OFFQ);
  f16* QL = QH + SZX;
  f16* KH = QL + SZX;
  f16* KL = KH + SZX;
  float* kk = (float*)(ws + OFFK2);

  k_split_w<<<dim3(E_ * E_ / 256), 256, 0, stream>>>(Wq, Wk, WqH, WqL, WkH, WkL);
  k_tsplit<<<dim3(E_ / 64, N_ / 64, B_ * 2), dim3(64, 4), 0, stream>>>(
      src_emb, tgt_emb, XqH, XqL, XkH, XkL);
  k_proj<<<dim3(N_ / 128, E_ / 128, B_ * 2), 256, 0, stream>>>(
      XqH, XqL, XkH, XkL, WqH, WqL, WkH, WkL, bq, bk, QH, QL, KH, KL);
  k_kk<<<dim3(B_ * M_ / 4), 256, 0, stream>>>(KH, KL, kk);
  for (int c = 0; c < N_ / NC_; ++c) {
    k_sgemm<<<dim3(NC_ / 128, M_ / 128, B_), 256, 0, stream>>>(
        QH, QL, KH, KL, kk, Schunk, c * NC_);
    k_softpv<<<dim3(B_ * NC_), 256, 0, stream>>>(Schunk, tgt, out, c * NC_);
  }
  k_copy<<<dim3(B_ * 3 * N_ / 256), 256, 0, stream>>>(src, out);
}

// Round 2
// 299.666 us; speedup vs baseline: 1.5283x; 1.5283x over previous
//
#include <hip/hip_runtime.h>

// VcpAtt: q = Wq@src_emb + bq ; k = Wk@tgt_emb + bk ;
// scores = softmax_m(2*q.k - ||k||^2)  (||q||^2 cancels in softmax)
// out = [src (copy), src_corr = tgt @ scores^T]
//
// fp16 hi/lo split (3-pass MFMA) for fp32-grade accuracy on gfx950.
// GEMMs use the m97 structure: 128x128 tile, BK=32, global_load_lds (16B),
// H/L-interleaved XOR-swizzled LDS rows -> conflict-free ds_read_b128.

typedef _Float16 f16;
typedef __attribute__((ext_vector_type(8))) _Float16 f16x8;
typedef __attribute__((ext_vector_type(4))) float f32x4;

constexpr int B_ = 2, E_ = 512, N_ = 4096, M_ = 4096;
constexpr int NC_ = 1024;            // n-chunk for S materialization
constexpr float WSCALE = 64.0f;      // keep W lo-residuals out of f16 denormal range

__device__ __forceinline__ f32x4 mfma16(f16x8 a, f16x8 b, f32x4 c) {
  return __builtin_amdgcn_mfma_f32_16x16x32_f16(a, b, c, 0, 0, 0);
}

__device__ __forceinline__ void gll16(const void* g, void* l) {
  __builtin_amdgcn_global_load_lds(
      (const __attribute__((address_space(1))) unsigned int*)g,
      (__attribute__((address_space(3))) unsigned int*)l, 16, 0, 0);
}

// ---- shared 128x128 K-loop (fp16 h/l, 3-pass) ---------------------------
// LDS per region: 128 rows x 128B. Row = 8 slots of 16B; logical slot q<4
// holds H elements [q*8, q*8+8) of the 32-wide K-block, q>=4 holds L
// elements [(q-4)*8, ...). Physical slot p = q ^ (row&7)  (bank swizzle).
// Staged with linear LDS dest + inverse-swizzled per-lane global source.
__device__ __forceinline__ void gemm_hl(
    const f16* __restrict__ AH, const f16* __restrict__ AL,
    const f16* __restrict__ BH, const f16* __restrict__ BL,
    char* lds, f32x4 (&acc)[4][4])
{
  char* ldsA = lds;
  char* ldsB = lds + 16384;
  const int tid = threadIdx.x;
  const int l = tid & 63, w = tid >> 6;

  // staging duties: pass c covers rows c*32 + w*8 + (l>>3), phys slot l&7
  const int q = (l & 7) ^ (l >> 3);            // logical slot this lane fetches
  const int rA = w * 8 + (l >> 3);             // row within tile (pass 0)
  const size_t srcoff = (size_t)rA * E_ + (q & 3) * 8;
  const f16* sA = (q < 4 ? AH : AL) + srcoff;
  const f16* sB = (q < 4 ? BH : BL) + srcoff;
  char* dA = ldsA + w * 1024;
  char* dB = ldsB + w * 1024;

  // fragment read addresses (swizzled): H slot (l>>4), L slot 4+(l>>4)
  const int r15 = l & 15;
  const int pH16 = ((l >> 4) ^ (l & 7)) * 16;  // phys slot * 16 (row&7 == l&7... see below)
  const int wr = (w >> 1) * 64, wc = (w & 1) * 64;
  // frag row = wr + i*16 + r15  ->  row&7 = l&7 (wr, i*16 are multiples of 8/16)
  const char* rAh = ldsA + (wr + r15) * 128 + pH16;
  const char* rAl = ldsA + (wr + r15) * 128 + (pH16 ^ 64);
  const char* rBh = ldsB + (wc + r15) * 128 + pH16;
  const char* rBl = ldsB + (wc + r15) * 128 + (pH16 ^ 64);

  for (int e0 = 0; e0 < E_; e0 += 32) {
#pragma unroll
    for (int c = 0; c < 4; ++c) {
      gll16(sA + (size_t)c * 32 * E_, dA + c * 4096);
      gll16(sB + (size_t)c * 32 * E_, dB + c * 4096);
    }
    sA += 32; sB += 32;
    __syncthreads();                 // drains vmcnt: staged tile visible
    f16x8 ah[4], al[4], bh[4], bl[4];
#pragma unroll
    for (int i = 0; i < 4; ++i) {
      ah[i] = *(const f16x8*)(rAh + i * 2048);
      al[i] = *(const f16x8*)(rAl + i * 2048);
      bh[i] = *(const f16x8*)(rBh + i * 2048);
      bl[i] = *(const f16x8*)(rBl + i * 2048);
    }
#pragma unroll
    for (int i = 0; i < 4; ++i)
#pragma unroll
      for (int j = 0; j < 4; ++j) {
        acc[i][j] = mfma16(ah[i], bh[j], acc[i][j]);
        acc[i][j] = mfma16(ah[i], bl[j], acc[i][j]);
        acc[i][j] = mfma16(al[i], bh[j], acc[i][j]);
      }
    __syncthreads();                 // tile reads done before next stage
  }
}

// ---- split W into f16 hi/lo (scaled by WSCALE) --------------------------
__global__ void k_split_w(const float* __restrict__ Wq, const float* __restrict__ Wk,
                          f16* __restrict__ WqH, f16* __restrict__ WqL,
                          f16* __restrict__ WkH, f16* __restrict__ WkL) {
  int i = blockIdx.x * 256 + threadIdx.x;      // grid covers E_*E_
  float a = Wq[i] * WSCALE;
  f16 ah = (f16)a; WqH[i] = ah; WqL[i] = (f16)(a - (float)ah);
  float b = Wk[i] * WSCALE;
  f16 bh = (f16)b; WkH[i] = bh; WkL[i] = (f16)(b - (float)bh);
}

// ---- transpose (E,N) fp32 -> (N,E) f16 hi/lo ----------------------------
__global__ void k_tsplit(const float* __restrict__ Xq, const float* __restrict__ Xk,
                         f16* __restrict__ XqH, f16* __restrict__ XqL,
                         f16* __restrict__ XkH, f16* __restrict__ XkL) {
  __shared__ float tile[64][65];
  const int b = blockIdx.z >> 1, which = blockIdx.z & 1;
  const float* X = (which ? Xk : Xq) + (size_t)b * E_ * N_;
  f16* H = (which ? XkH : XqH) + (size_t)b * N_ * E_;
  f16* L = (which ? XkL : XqL) + (size_t)b * N_ * E_;
  const int e0 = blockIdx.x * 64, n0 = blockIdx.y * 64;
  const int x = threadIdx.x, y = threadIdx.y;
#pragma unroll
  for (int j = 0; j < 16; ++j) {
    int e = y * 16 + j;
    tile[e][x] = X[(size_t)(e0 + e) * N_ + n0 + x];   // coalesced along n
  }
  __syncthreads();
#pragma unroll
  for (int j = 0; j < 16; ++j) {
    int nl = y * 16 + j;
    float v = tile[x][nl];
    f16 h = (f16)v;
    H[(size_t)(n0 + nl) * E_ + e0 + x] = h;           // coalesced along e
    L[(size_t)(n0 + nl) * E_ + e0 + x] = (f16)(v - (float)h);
  }
}

// ---- projection GEMM: O[n][f] = sum_e Xt[n][e]*W[f][e]*(1/WSCALE) + bias[f]
__global__ __launch_bounds__(256) void k_proj(
    const f16* __restrict__ XqH, const f16* __restrict__ XqL,
    const f16* __restrict__ XkH, const f16* __restrict__ XkL,
    const f16* __restrict__ WqH, const f16* __restrict__ WqL,
    const f16* __restrict__ WkH, const f16* __restrict__ WkL,
    const float* __restrict__ bq, const float* __restrict__ bk,
    f16* __restrict__ QH, f16* __restrict__ QL,
    f16* __restrict__ KH, f16* __restrict__ KL) {
  __shared__ char lds[32768];
  const int b = blockIdx.z >> 1, kind = blockIdx.z & 1;
  const f16* AH = (kind ? XkH : XqH) + (size_t)b * N_ * E_;
  const f16* AL = (kind ? XkL : XqL) + (size_t)b * N_ * E_;
  const f16* BH = kind ? WkH : WqH;
  const f16* BL = kind ? WkL : WqL;
  const float* bias = kind ? bk : bq;
  f16* OH = (kind ? KH : QH) + (size_t)b * N_ * E_;
  f16* OL = (kind ? KL : QL) + (size_t)b * N_ * E_;
  const int n0 = blockIdx.x * 128, f0 = blockIdx.y * 128;
  const int lane = threadIdx.x & 63, w = threadIdx.x >> 6;
  const int wr = (w >> 1) * 64, wc = (w & 1) * 64;
  const int r15 = lane & 15;

  f32x4 acc[4][4] = {};
  gemm_hl(AH + (size_t)n0 * E_, AL + (size_t)n0 * E_,
          BH + (size_t)f0 * E_, BL + (size_t)f0 * E_, lds, acc);

  const int rowg = (lane >> 4) * 4;
#pragma unroll
  for (int j = 0; j < 4; ++j) {
    int f = f0 + wc + j * 16 + r15;            // C/D: col = lane&15
    float bv = bias[f];
#pragma unroll
    for (int i = 0; i < 4; ++i) {
#pragma unroll
      for (int r = 0; r < 4; ++r) {
        int n = n0 + wr + i * 16 + rowg + r;   // C/D: row = (lane>>4)*4 + r
        float qv = acc[i][j][r] * (1.0f / WSCALE) + bv;
        f16 h = (f16)qv;
        OH[(size_t)n * E_ + f] = h;
        OL[(size_t)n * E_ + f] = (f16)(qv - (float)h);
      }
    }
  }
}

// ---- kk[b*M+m] = sum_f k^2 ----------------------------------------------
__global__ void k_kk(const f16* __restrict__ KH, const f16* __restrict__ KL,
                     float* __restrict__ kk) {
  int row = blockIdx.x * 4 + (threadIdx.x >> 6);   // b*M + m
  int lane = threadIdx.x & 63;
  f16x8 h8 = *(const f16x8*)(KH + (size_t)row * E_ + lane * 8);
  f16x8 l8 = *(const f16x8*)(KL + (size_t)row * E_ + lane * 8);
  float s = 0.f;
#pragma unroll
  for (int i = 0; i < 8; ++i) {
    float v = (float)h8[i] + (float)l8[i];
    s += v * v;
  }
#pragma unroll
  for (int o = 32; o; o >>= 1) s += __shfl_xor(s, o);
  if (lane == 0) kk[row] = s;
}

// ---- S GEMM (chunked): S[b][nl][m] = 2*sum_e q*k - kk[b*M+m] ------------
__global__ __launch_bounds__(256) void k_sgemm(
    const f16* __restrict__ QH, const f16* __restrict__ QL,
    const f16* __restrict__ KH, const f16* __restrict__ KL,
    const float* __restrict__ kk, float* __restrict__ S, int n_base) {
  __shared__ char lds[32768];
  const int b = blockIdx.z;
  const int n0 = blockIdx.x * 128, m0 = blockIdx.y * 128;
  const int lane = threadIdx.x & 63, w = threadIdx.x >> 6;
  const int wr = (w >> 1) * 64, wc = (w & 1) * 64;
  const int r15 = lane & 15;
  const f16* AH = QH + ((size_t)b * N_ + n_base + n0) * E_;
  const f16* AL = QL + ((size_t)b * N_ + n_base + n0) * E_;
  const f16* BH = KH + ((size_t)b * M_ + m0) * E_;
  const f16* BL = KL + ((size_t)b * M_ + m0) * E_;

  f32x4 acc[4][4] = {};
  gemm_hl(AH, AL, BH, BL, lds, acc);

  const int rowg = (lane >> 4) * 4;
#pragma unroll
  for (int j = 0; j < 4; ++j) {
    int m = m0 + wc + j * 16 + r15;
    float kv = kk[(size_t)b * M_ + m];
#pragma unroll
    for (int i = 0; i < 4; ++i)
#pragma unroll
      for (int r = 0; r < 4; ++r) {
        int nl = n0 + wr + i * 16 + rowg + r;
        S[((size_t)b * NC_ + nl) * M_ + m] = 2.0f * acc[i][j][r] - kv;
      }
  }
}

// ---- row softmax + PV (V = tgt rows, 3 dims) ----------------------------
__global__ __launch_bounds__(256) void k_softpv(const float* __restrict__ S,
                                                const float* __restrict__ tgt,
                                                float* __restrict__ out, int n_base) {
  const int row = blockIdx.x;                // b*NC_ + nloc
  const int b = row / NC_, nloc = row % NC_;
  const int n = n_base + nloc;
  const float* srow = S + (size_t)row * M_;
  const int t = threadIdx.x;
  float4 v[4];
  float mx = -3.0e38f;
#pragma unroll
  for (int k = 0; k < 4; ++k) {
    v[k] = *(const float4*)(srow + (size_t)(k * 256 + t) * 4);
    mx = fmaxf(mx, fmaxf(fmaxf(v[k].x, v[k].y), fmaxf(v[k].z, v[k].w)));
  }
#pragma unroll
  for (int o = 32; o; o >>= 1) mx = fmaxf(mx, __shfl_xor(mx, o));
  __shared__ float wred[4];
  __shared__ float facc[4][4];
  const int w = t >> 6, lane = t & 63;
  if (lane == 0) wred[w] = mx;
  __syncthreads();
  mx = fmaxf(fmaxf(wred[0], wred[1]), fmaxf(wred[2], wred[3]));
  const float* t0 = tgt + ((size_t)b * 3 + 0) * M_;
  const float* t1 = tgt + ((size_t)b * 3 + 1) * M_;
  const float* t2 = tgt + ((size_t)b * 3 + 2) * M_;
  float sum = 0, p0 = 0, p1 = 0, p2 = 0;
#pragma unroll
  for (int k = 0; k < 4; ++k) {
    int m = (k * 256 + t) * 4;
    float4 g0 = *(const float4*)(t0 + m);
    float4 g1 = *(const float4*)(t1 + m);
    float4 g2 = *(const float4*)(t2 + m);
    float4 sv = v[k];
    float e0 = __expf(sv.x - mx), e1 = __expf(sv.y - mx),
          e2 = __expf(sv.z - mx), e3 = __expf(sv.w - mx);
    sum += e0 + e1 + e2 + e3;
    p0 += e0 * g0.x + e1 * g0.y + e2 * g0.z + e3 * g0.w;
    p1 += e0 * g1.x + e1 * g1.y + e2 * g1.z + e3 * g1.w;
    p2 += e0 * g2.x + e1 * g2.y + e2 * g2.z + e3 * g2.w;
  }
#pragma unroll
  for (int o = 32; o; o >>= 1) {
    sum += __shfl_xor(sum, o);
    p0 += __shfl_xor(p0, o);
    p1 += __shfl_xor(p1, o);
    p2 += __shfl_xor(p2, o);
  }
  if (lane == 0) { facc[w][0] = sum; facc[w][1] = p0; facc[w][2] = p1; facc[w][3] = p2; }
  __syncthreads();
  if (t == 0) {
    float S0 = facc[0][0] + facc[1][0] + facc[2][0] + facc[3][0];
    float P0 = facc[0][1] + facc[1][1] + facc[2][1] + facc[3][1];
    float P1 = facc[0][2] + facc[1][2] + facc[2][2] + facc[3][2];
    float P2 = facc[0][3] + facc[1][3] + facc[2][3] + facc[3][3];
    float inv = 1.0f / S0;
    float* oc = out + (size_t)B_ * 3 * N_;
    oc[((size_t)b * 3 + 0) * N_ + n] = P0 * inv;
    oc[((size_t)b * 3 + 1) * N_ + n] = P1 * inv;
    oc[((size_t)b * 3 + 2) * N_ + n] = P2 * inv;
  }
}

// ---- src passthrough ----------------------------------------------------
__global__ void k_copy(const float* __restrict__ src, float* __restrict__ out) {
  int i = blockIdx.x * 256 + threadIdx.x;
  out[i] = src[i];
}

extern "C" void kernel_launch(void* const* d_in, const int* in_sizes, int n_in,
                              void* d_out, int out_size, void* d_ws, size_t ws_size,
                              hipStream_t stream) {
  const float* src_emb = (const float*)d_in[0];
  const float* tgt_emb = (const float*)d_in[1];
  const float* src     = (const float*)d_in[2];
  const float* tgt     = (const float*)d_in[3];
  const float* Wq      = (const float*)d_in[4];
  const float* bq      = (const float*)d_in[5];
  const float* Wk      = (const float*)d_in[6];
  const float* bk      = (const float*)d_in[7];
  float* out = (float*)d_out;

  // workspace layout (Xt region aliases Schunk: Xt dead after k_proj)
  constexpr size_t SZX = (size_t)B_ * N_ * E_;        // elements per f16 array
  constexpr size_t R0   = 4 * SZX * sizeof(f16);      // 33,554,432 == Schunk bytes
  constexpr size_t OFFW = R0;
  constexpr size_t OFFQ = OFFW + 4 * (size_t)E_ * E_ * sizeof(f16);
  constexpr size_t OFFK2 = OFFQ + 4 * SZX * sizeof(f16);
  constexpr size_t NEED = OFFK2 + (size_t)B_ * M_ * sizeof(float);
  if (ws_size < NEED) return;  // insufficient scratch; fail loudly via validation

  char* ws = (char*)d_ws;
  float* Schunk = (float*)(ws);
  f16* XqH = (f16*)(ws);
  f16* XqL = XqH + SZX;
  f16* XkH = XqL + SZX;
  f16* XkL = XkH + SZX;
  f16* WqH = (f16*)(ws + OFFW);
  f16* WqL = WqH + (size_t)E_ * E_;
  f16* WkH = WqL + (size_t)E_ * E_;
  f16* WkL = WkH + (size_t)E_ * E_;
  f16* QH = (f16*)(ws + OFFQ);
  f16* QL = QH + SZX;
  f16* KH = QL + SZX;
  f16* KL = KH + SZX;
  float* kk = (float*)(ws + OFFK2);

  k_split_w<<<dim3(E_ * E_ / 256), 256, 0, stream>>>(Wq, Wk, WqH, WqL, WkH, WkL);
  k_tsplit<<<dim3(E_ / 64, N_ / 64, B_ * 2), dim3(64, 4), 0, stream>>>(
      src_emb, tgt_emb, XqH, XqL, XkH, XkL);
  k_proj<<<dim3(N_ / 128, E_ / 128, B_ * 2), 256, 0, stream>>>(
      XqH, XqL, XkH, XkL, WqH, WqL, WkH, WkL, bq, bk, QH, QL, KH, KL);
  k_kk<<<dim3(B_ * M_ / 4), 256, 0, stream>>>(KH, KL, kk);
  for (int c = 0; c < N_ / NC_; ++c) {
    k_sgemm<<<dim3(NC_ / 128, M_ / 128, B_), 256, 0, stream>>>(
        QH, QL, KH, KL, kk, Schunk, c * NC_);
    k_softpv<<<dim3(B_ * NC_), 256, 0, stream>>>(Schunk, tgt, out, c * NC_);
  }
  k_copy<<<dim3(B_ * 3 * N_ / 256), 256, 0, stream>>>(src, out);
}

// Round 3
// 250.121 us; speedup vs baseline: 1.8310x; 1.1981x over previous
//
#include <hip/hip_runtime.h>

// VcpAtt: q = Wq@src_emb + bq ; k = Wk@tgt_emb + bk ;
// scores = softmax_m(2*q.k - ||k||^2)  (||q||^2 cancels in softmax)
// out = [src (copy), src_corr = tgt @ scores^T]
//
// fp16 hi/lo split (3-pass MFMA) for fp32-grade accuracy on gfx950.
// Flash-fused S GEMM + online softmax + PV (V is only 3-wide), m-chunked
// across blocks with a tiny partial-combine kernel.

typedef _Float16 f16;
typedef __attribute__((ext_vector_type(8))) _Float16 f16x8;
typedef __attribute__((ext_vector_type(4))) float f32x4;

constexpr int B_ = 2, E_ = 512, N_ = 4096, M_ = 4096;
constexpr int MCH = 8;               // m-chunks (512 cols each)
constexpr float WSCALE = 64.0f;      // keep W lo-residuals out of f16 denormal range

__device__ __forceinline__ f32x4 mfma16(f16x8 a, f16x8 b, f32x4 c) {
  return __builtin_amdgcn_mfma_f32_16x16x32_f16(a, b, c, 0, 0, 0);
}

__device__ __forceinline__ void gll16(const void* g, void* l) {
  __builtin_amdgcn_global_load_lds(
      (const __attribute__((address_space(1))) unsigned int*)g,
      (__attribute__((address_space(3))) unsigned int*)l, 16, 0, 0);
}

// ---- LDS tile layout (both A and B regions, 16KB each) ------------------
// 128 rows x 128B. Row = 8 slots of 16B; logical slot q<4 holds H elements
// [q*8, q*8+8) of the 32-wide K-block, q>=4 holds L. Physical slot
// p = q ^ (row&7). Staged linear-dest via inverse-swizzled global source.

// ---- 2x2-wave 128x128 K-loop (for k_proj) -------------------------------
__device__ __forceinline__ void gemm_hl22(
    const f16* __restrict__ AH, const f16* __restrict__ AL,
    const f16* __restrict__ BH, const f16* __restrict__ BL,
    char* lds, f32x4 (&acc)[4][4])
{
  char* ldsA = lds;
  char* ldsB = lds + 16384;
  const int l = threadIdx.x & 63, w = threadIdx.x >> 6;
  const int q = (l & 7) ^ (l >> 3);
  const int rA = w * 8 + (l >> 3);
  const size_t srcoff = (size_t)rA * E_ + (q & 3) * 8;
  const f16* sA = (q < 4 ? AH : AL) + srcoff;
  const f16* sB = (q < 4 ? BH : BL) + srcoff;
  char* dA = ldsA + w * 1024;
  char* dB = ldsB + w * 1024;

  const int r15 = l & 15;
  const int pH16 = ((l >> 4) ^ (l & 7)) * 16;
  const int wr = (w >> 1) * 64, wc = (w & 1) * 64;
  const char* rAh = ldsA + (wr + r15) * 128 + pH16;
  const char* rAl = ldsA + (wr + r15) * 128 + (pH16 ^ 64);
  const char* rBh = ldsB + (wc + r15) * 128 + pH16;
  const char* rBl = ldsB + (wc + r15) * 128 + (pH16 ^ 64);

  for (int e0 = 0; e0 < E_; e0 += 32) {
#pragma unroll
    for (int c = 0; c < 4; ++c) {
      gll16(sA + (size_t)c * 32 * E_, dA + c * 4096);
      gll16(sB + (size_t)c * 32 * E_, dB + c * 4096);
    }
    sA += 32; sB += 32;
    __syncthreads();
    f16x8 ah[4], al[4], bh[4], bl[4];
#pragma unroll
    for (int i = 0; i < 4; ++i) {
      ah[i] = *(const f16x8*)(rAh + i * 2048);
      al[i] = *(const f16x8*)(rAl + i * 2048);
      bh[i] = *(const f16x8*)(rBh + i * 2048);
      bl[i] = *(const f16x8*)(rBl + i * 2048);
    }
#pragma unroll
    for (int i = 0; i < 4; ++i)
#pragma unroll
      for (int j = 0; j < 4; ++j) {
        acc[i][j] = mfma16(ah[i], bh[j], acc[i][j]);
        acc[i][j] = mfma16(ah[i], bl[j], acc[i][j]);
        acc[i][j] = mfma16(al[i], bh[j], acc[i][j]);
      }
    __syncthreads();
  }
}

// ---- 4x1-wave 128x128 K-loop (for k_flash: rows wave-local) -------------
__device__ __forceinline__ void gemm_hl41(
    const f16* __restrict__ AH, const f16* __restrict__ AL,
    const f16* __restrict__ BH, const f16* __restrict__ BL,
    char* lds, f32x4 (&acc)[2][8])
{
  char* ldsA = lds;
  char* ldsB = lds + 16384;
  const int l = threadIdx.x & 63, w = threadIdx.x >> 6;
  const int q = (l & 7) ^ (l >> 3);
  const int rA = w * 8 + (l >> 3);
  const size_t srcoff = (size_t)rA * E_ + (q & 3) * 8;
  const f16* sA = (q < 4 ? AH : AL) + srcoff;
  const f16* sB = (q < 4 ? BH : BL) + srcoff;
  char* dA = ldsA + w * 1024;
  char* dB = ldsB + w * 1024;

  const int r15 = l & 15;
  const int pH16 = ((l >> 4) ^ (l & 7)) * 16;
  const char* rAh = ldsA + (w * 32 + r15) * 128 + pH16;
  const char* rAl = ldsA + (w * 32 + r15) * 128 + (pH16 ^ 64);
  const char* rBh = ldsB + r15 * 128 + pH16;
  const char* rBl = ldsB + r15 * 128 + (pH16 ^ 64);

  for (int e0 = 0; e0 < E_; e0 += 32) {
#pragma unroll
    for (int c = 0; c < 4; ++c) {
      gll16(sA + (size_t)c * 32 * E_, dA + c * 4096);
      gll16(sB + (size_t)c * 32 * E_, dB + c * 4096);
    }
    sA += 32; sB += 32;
    __syncthreads();
    f16x8 ah0 = *(const f16x8*)(rAh);
    f16x8 ah1 = *(const f16x8*)(rAh + 2048);
    f16x8 al0 = *(const f16x8*)(rAl);
    f16x8 al1 = *(const f16x8*)(rAl + 2048);
#pragma unroll
    for (int j = 0; j < 8; ++j) {
      f16x8 bh = *(const f16x8*)(rBh + j * 2048);
      f16x8 bl = *(const f16x8*)(rBl + j * 2048);
      acc[0][j] = mfma16(ah0, bh, acc[0][j]);
      acc[1][j] = mfma16(ah1, bh, acc[1][j]);
      acc[0][j] = mfma16(ah0, bl, acc[0][j]);
      acc[1][j] = mfma16(ah1, bl, acc[1][j]);
      acc[0][j] = mfma16(al0, bh, acc[0][j]);
      acc[1][j] = mfma16(al1, bh, acc[1][j]);
    }
    __syncthreads();
  }
}

// ---- split W into f16 hi/lo (scaled by WSCALE) --------------------------
__global__ void k_split_w(const float* __restrict__ Wq, const float* __restrict__ Wk,
                          f16* __restrict__ WqH, f16* __restrict__ WqL,
                          f16* __restrict__ WkH, f16* __restrict__ WkL) {
  int i = blockIdx.x * 256 + threadIdx.x;
  float a = Wq[i] * WSCALE;
  f16 ah = (f16)a; WqH[i] = ah; WqL[i] = (f16)(a - (float)ah);
  float b = Wk[i] * WSCALE;
  f16 bh = (f16)b; WkH[i] = bh; WkL[i] = (f16)(b - (float)bh);
}

// ---- transpose (E,N) fp32 -> (N,E) f16 hi/lo ----------------------------
__global__ void k_tsplit(const float* __restrict__ Xq, const float* __restrict__ Xk,
                         f16* __restrict__ XqH, f16* __restrict__ XqL,
                         f16* __restrict__ XkH, f16* __restrict__ XkL) {
  __shared__ float tile[64][65];
  const int b = blockIdx.z >> 1, which = blockIdx.z & 1;
  const float* X = (which ? Xk : Xq) + (size_t)b * E_ * N_;
  f16* H = (which ? XkH : XqH) + (size_t)b * N_ * E_;
  f16* L = (which ? XkL : XqL) + (size_t)b * N_ * E_;
  const int e0 = blockIdx.x * 64, n0 = blockIdx.y * 64;
  const int x = threadIdx.x, y = threadIdx.y;
#pragma unroll
  for (int j = 0; j < 16; ++j) {
    int e = y * 16 + j;
    tile[e][x] = X[(size_t)(e0 + e) * N_ + n0 + x];
  }
  __syncthreads();
#pragma unroll
  for (int j = 0; j < 16; ++j) {
    int nl = y * 16 + j;
    float v = tile[x][nl];
    f16 h = (f16)v;
    H[(size_t)(n0 + nl) * E_ + e0 + x] = h;
    L[(size_t)(n0 + nl) * E_ + e0 + x] = (f16)(v - (float)h);
  }
}

// ---- projection GEMM ----------------------------------------------------
__global__ __launch_bounds__(256) void k_proj(
    const f16* __restrict__ XqH, const f16* __restrict__ XqL,
    const f16* __restrict__ XkH, const f16* __restrict__ XkL,
    const f16* __restrict__ WqH, const f16* __restrict__ WqL,
    const f16* __restrict__ WkH, const f16* __restrict__ WkL,
    const float* __restrict__ bq, const float* __restrict__ bk,
    f16* __restrict__ QH, f16* __restrict__ QL,
    f16* __restrict__ KH, f16* __restrict__ KL) {
  __shared__ char lds[32768];
  const int b = blockIdx.z >> 1, kind = blockIdx.z & 1;
  const f16* AH = (kind ? XkH : XqH) + (size_t)b * N_ * E_;
  const f16* AL = (kind ? XkL : XqL) + (size_t)b * N_ * E_;
  const f16* BH = kind ? WkH : WqH;
  const f16* BL = kind ? WkL : WqL;
  const float* bias = kind ? bk : bq;
  f16* OH = (kind ? KH : QH) + (size_t)b * N_ * E_;
  f16* OL = (kind ? KL : QL) + (size_t)b * N_ * E_;
  const int n0 = blockIdx.x * 128, f0 = blockIdx.y * 128;
  const int lane = threadIdx.x & 63, w = threadIdx.x >> 6;
  const int wr = (w >> 1) * 64, wc = (w & 1) * 64;
  const int r15 = lane & 15;

  f32x4 acc[4][4] = {};
  gemm_hl22(AH + (size_t)n0 * E_, AL + (size_t)n0 * E_,
            BH + (size_t)f0 * E_, BL + (size_t)f0 * E_, lds, acc);

  const int rowg = (lane >> 4) * 4;
#pragma unroll
  for (int j = 0; j < 4; ++j) {
    int f = f0 + wc + j * 16 + r15;
    float bv = bias[f];
#pragma unroll
    for (int i = 0; i < 4; ++i) {
#pragma unroll
      for (int r = 0; r < 4; ++r) {
        int n = n0 + wr + i * 16 + rowg + r;
        float qv = acc[i][j][r] * (1.0f / WSCALE) + bv;
        f16 h = (f16)qv;
        OH[(size_t)n * E_ + f] = h;
        OL[(size_t)n * E_ + f] = (f16)(qv - (float)h);
      }
    }
  }
}

// ---- kk[b*M+m] = sum_f k^2 ----------------------------------------------
__global__ void k_kk(const f16* __restrict__ KH, const f16* __restrict__ KL,
                     float* __restrict__ kk) {
  int row = blockIdx.x * 4 + (threadIdx.x >> 6);
  int lane = threadIdx.x & 63;
  f16x8 h8 = *(const f16x8*)(KH + (size_t)row * E_ + lane * 8);
  f16x8 l8 = *(const f16x8*)(KL + (size_t)row * E_ + lane * 8);
  float s = 0.f;
#pragma unroll
  for (int i = 0; i < 8; ++i) {
    float v = (float)h8[i] + (float)l8[i];
    s += v * v;
  }
#pragma unroll
  for (int o = 32; o; o >>= 1) s += __shfl_xor(s, o);
  if (lane == 0) kk[row] = s;
}

// ---- flash: S-tile GEMM + online softmax + PV over one m-chunk ----------
// grid (N/128, MCH, B); per-chunk partials {max,sum,p0,p1,p2} per row.
__global__ __launch_bounds__(256, 2) void k_flash(
    const f16* __restrict__ QH, const f16* __restrict__ QL,
    const f16* __restrict__ KH, const f16* __restrict__ KL,
    const float* __restrict__ kk, const float* __restrict__ tgt,
    float* __restrict__ part) {
  __shared__ char lds[40960];
  float* kks = (float*)(lds + 32768);   // 512 f32
  float* tgs = (float*)(lds + 34816);   // 3*512 f32
  const int b = blockIdx.z;
  const int n0 = blockIdx.x * 128;
  const int mc = blockIdx.y;
  const int m0c = mc * 512;
  const int tid = threadIdx.x, l = tid & 63, w = tid >> 6;
  const int r15 = l & 15;

  for (int i = tid; i < 512; i += 256) kks[i] = kk[(size_t)b * M_ + m0c + i];
  for (int i = tid; i < 1536; i += 256) {
    int d = i >> 9, m = i & 511;
    tgs[i] = tgt[((size_t)b * 3 + d) * M_ + m0c + m];
  }
  // visibility: first __syncthreads inside gemm_hl41 orders these writes

  const f16* AH = QH + ((size_t)b * N_ + n0) * E_;
  const f16* AL = QL + ((size_t)b * N_ + n0) * E_;

  float mrun[8], psum[8], pp0[8], pp1[8], pp2[8];
#pragma unroll
  for (int x = 0; x < 8; ++x) {
    mrun[x] = -3.0e38f; psum[x] = 0.f; pp0[x] = 0.f; pp1[x] = 0.f; pp2[x] = 0.f;
  }

  for (int mt = 0; mt < 4; ++mt) {
    const int m0 = m0c + mt * 128;
    const f16* BH = KH + ((size_t)b * M_ + m0) * E_;
    const f16* BL = KL + ((size_t)b * M_ + m0) * E_;
    f32x4 acc[2][8] = {};
    gemm_hl41(AH, AL, BH, BL, lds, acc);

    // per-lane col data for this m-tile (reused across all 8 rows)
    float kv[8], tv0[8], tv1[8], tv2[8];
#pragma unroll
    for (int j = 0; j < 8; ++j) {
      int ml = mt * 128 + j * 16 + r15;
      kv[j] = kks[ml];
      tv0[j] = tgs[ml];
      tv1[j] = tgs[512 + ml];
      tv2[j] = tgs[1024 + ml];
    }
#pragma unroll
    for (int i = 0; i < 2; ++i) {
#pragma unroll
      for (int r = 0; r < 4; ++r) {
        const int x = i * 4 + r;
        float s[8];
        float rmax = -3.0e38f;
#pragma unroll
        for (int j = 0; j < 8; ++j) {
          s[j] = 2.0f * acc[i][j][r] - kv[j];
          rmax = fmaxf(rmax, s[j]);
        }
        rmax = fmaxf(rmax, __shfl_xor(rmax, 1));
        rmax = fmaxf(rmax, __shfl_xor(rmax, 2));
        rmax = fmaxf(rmax, __shfl_xor(rmax, 4));
        rmax = fmaxf(rmax, __shfl_xor(rmax, 8));
        float nm = fmaxf(mrun[x], rmax);
        float sc = __expf(mrun[x] - nm);
        mrun[x] = nm;
        psum[x] *= sc; pp0[x] *= sc; pp1[x] *= sc; pp2[x] *= sc;
#pragma unroll
        for (int j = 0; j < 8; ++j) {
          float e = __expf(s[j] - nm);
          psum[x] += e;
          pp0[x] += e * tv0[j];
          pp1[x] += e * tv1[j];
          pp2[x] += e * tv2[j];
        }
      }
    }
  }

  // reduce partial sums across the 16-lane row group; write partials
#pragma unroll
  for (int x = 0; x < 8; ++x) {
#pragma unroll
    for (int o = 1; o <= 8; o <<= 1) {
      psum[x] += __shfl_xor(psum[x], o);
      pp0[x] += __shfl_xor(pp0[x], o);
      pp1[x] += __shfl_xor(pp1[x], o);
      pp2[x] += __shfl_xor(pp2[x], o);
    }
  }
  if (r15 == 0) {
    const int hi = l >> 4;
#pragma unroll
    for (int x = 0; x < 8; ++x) {
      int i = x >> 2, r = x & 3;
      int n = n0 + w * 32 + i * 16 + hi * 4 + r;
      size_t pb = ((size_t)(b * N_ + n) * MCH + mc) * 5;
      part[pb + 0] = mrun[x];
      part[pb + 1] = psum[x];
      part[pb + 2] = pp0[x];
      part[pb + 3] = pp1[x];
      part[pb + 4] = pp2[x];
    }
  }
}

// ---- combine per-chunk partials -> output -------------------------------
__global__ void k_comb(const float* __restrict__ part, float* __restrict__ out) {
  int idx = blockIdx.x * 256 + threadIdx.x;     // b*N + n
  int b = idx >> 12, n = idx & (N_ - 1);
  const float* p = part + (size_t)idx * MCH * 5;
  float M = -3.0e38f;
#pragma unroll
  for (int c = 0; c < MCH; ++c) M = fmaxf(M, p[c * 5]);
  float S = 0.f, P0 = 0.f, P1 = 0.f, P2 = 0.f;
#pragma unroll
  for (int c = 0; c < MCH; ++c) {
    float e = __expf(p[c * 5] - M);
    S += p[c * 5 + 1] * e;
    P0 += p[c * 5 + 2] * e;
    P1 += p[c * 5 + 3] * e;
    P2 += p[c * 5 + 4] * e;
  }
  float inv = 1.0f / S;
  float* oc = out + (size_t)B_ * 3 * N_;
  oc[((size_t)b * 3 + 0) * N_ + n] = P0 * inv;
  oc[((size_t)b * 3 + 1) * N_ + n] = P1 * inv;
  oc[((size_t)b * 3 + 2) * N_ + n] = P2 * inv;
}

// ---- src passthrough ----------------------------------------------------
__global__ void k_copy(const float* __restrict__ src, float* __restrict__ out) {
  int i = blockIdx.x * 256 + threadIdx.x;
  out[i] = src[i];
}

extern "C" void kernel_launch(void* const* d_in, const int* in_sizes, int n_in,
                              void* d_out, int out_size, void* d_ws, size_t ws_size,
                              hipStream_t stream) {
  const float* src_emb = (const float*)d_in[0];
  const float* tgt_emb = (const float*)d_in[1];
  const float* src     = (const float*)d_in[2];
  const float* tgt     = (const float*)d_in[3];
  const float* Wq      = (const float*)d_in[4];
  const float* bq      = (const float*)d_in[5];
  const float* Wk      = (const float*)d_in[6];
  const float* bk      = (const float*)d_in[7];
  float* out = (float*)d_out;

  constexpr size_t SZX = (size_t)B_ * N_ * E_;        // elements per f16 array
  constexpr size_t OFFW = 4 * SZX * sizeof(f16);      // Xt region (dead after proj)
  constexpr size_t OFFQ = OFFW + 4 * (size_t)E_ * E_ * sizeof(f16);
  constexpr size_t OFFK2 = OFFQ + 4 * SZX * sizeof(f16);
  constexpr size_t OFFP = OFFK2 + (size_t)B_ * M_ * sizeof(float);
  constexpr size_t NEED = OFFP + (size_t)B_ * N_ * MCH * 5 * sizeof(float);
  if (ws_size < NEED) return;

  char* ws = (char*)d_ws;
  f16* XqH = (f16*)(ws);
  f16* XqL = XqH + SZX;
  f16* XkH = XqL + SZX;
  f16* XkL = XkH + SZX;
  f16* WqH = (f16*)(ws + OFFW);
  f16* WqL = WqH + (size_t)E_ * E_;
  f16* WkH = WqL + (size_t)E_ * E_;
  f16* WkL = WkH + (size_t)E_ * E_;
  f16* QH = (f16*)(ws + OFFQ);
  f16* QL = QH + SZX;
  f16* KH = QL + SZX;
  f16* KL = KH + SZX;
  float* kk = (float*)(ws + OFFK2);
  float* part = (float*)(ws + OFFP);

  k_split_w<<<dim3(E_ * E_ / 256), 256, 0, stream>>>(Wq, Wk, WqH, WqL, WkH, WkL);
  k_tsplit<<<dim3(E_ / 64, N_ / 64, B_ * 2), dim3(64, 4), 0, stream>>>(
      src_emb, tgt_emb, XqH, XqL, XkH, XkL);
  k_proj<<<dim3(N_ / 128, E_ / 128, B_ * 2), 256, 0, stream>>>(
      XqH, XqL, XkH, XkL, WqH, WqL, WkH, WkL, bq, bk, QH, QL, KH, KL);
  k_kk<<<dim3(B_ * M_ / 4), 256, 0, stream>>>(KH, KL, kk);
  k_flash<<<dim3(N_ / 128, MCH, B_), 256, 0, stream>>>(QH, QL, KH, KL, kk, tgt, part);
  k_comb<<<dim3(B_ * N_ / 256), 256, 0, stream>>>(part, out);
  k_copy<<<dim3(B_ * 3 * N_ / 256), 256, 0, stream>>>(src, out);
}

// Round 4
// 237.930 us; speedup vs baseline: 1.9248x; 1.0512x over previous
//
#include <hip/hip_runtime.h>

// VcpAtt: q = Wq@src_emb + bq ; k = Wk@tgt_emb + bk ;
// scores = softmax_m(2*q.k - ||k||^2)  (||q||^2 cancels in softmax)
// out = [src (copy), src_corr = tgt @ scores^T]
//
// fp16 hi/lo split (3-pass MFMA). Flash-fused S GEMM + online softmax + PV.
// K-loops double-buffered with counted vmcnt + raw s_barrier (T3-min/T4/T5).

typedef _Float16 f16;
typedef __attribute__((ext_vector_type(8))) _Float16 f16x8;
typedef __attribute__((ext_vector_type(4))) float f32x4;

constexpr int B_ = 2, E_ = 512, N_ = 4096, M_ = 4096;
constexpr int MCH = 8;               // m-chunks (512 cols each)
constexpr float WSCALE = 64.0f;

__device__ __forceinline__ f32x4 mfma16(f16x8 a, f16x8 b, f32x4 c) {
  return __builtin_amdgcn_mfma_f32_16x16x32_f16(a, b, c, 0, 0, 0);
}
__device__ __forceinline__ void gll16(const void* g, void* l) {
  __builtin_amdgcn_global_load_lds(
      (const __attribute__((address_space(1))) unsigned int*)g,
      (__attribute__((address_space(3))) unsigned int*)l, 16, 0, 0);
}
__device__ __forceinline__ void waitv8() { asm volatile("s_waitcnt vmcnt(8)" ::: "memory"); }
__device__ __forceinline__ void waitv0() { asm volatile("s_waitcnt vmcnt(0)" ::: "memory"); }

// LDS tile: 128 rows x 128B. Row = 8 slots of 16B; logical slot q<4 = H
// elems [q*8,q*8+8) of the 32-wide K-block, q>=4 = L. Phys slot = q^(row&7).
// Staged linear-dest (global_load_lds) via inverse-swizzled global source.

// ---- split W into f16 hi/lo (scaled) ------------------------------------
__global__ void k_split_w(const float* __restrict__ Wq, const float* __restrict__ Wk,
                          f16* __restrict__ WqH, f16* __restrict__ WqL,
                          f16* __restrict__ WkH, f16* __restrict__ WkL) {
  int i = blockIdx.x * 256 + threadIdx.x;
  float a = Wq[i] * WSCALE;
  f16 ah = (f16)a; WqH[i] = ah; WqL[i] = (f16)(a - (float)ah);
  float b = Wk[i] * WSCALE;
  f16 bh = (f16)b; WkH[i] = bh; WkL[i] = (f16)(b - (float)bh);
}

// ---- transpose (E,N) fp32 -> (N,E) f16 hi/lo ----------------------------
__global__ void k_tsplit(const float* __restrict__ Xq, const float* __restrict__ Xk,
                         f16* __restrict__ XqH, f16* __restrict__ XqL,
                         f16* __restrict__ XkH, f16* __restrict__ XkL) {
  __shared__ float tile[64][65];
  const int b = blockIdx.z >> 1, which = blockIdx.z & 1;
  const float* X = (which ? Xk : Xq) + (size_t)b * E_ * N_;
  f16* H = (which ? XkH : XqH) + (size_t)b * N_ * E_;
  f16* L = (which ? XkL : XqL) + (size_t)b * N_ * E_;
  const int e0 = blockIdx.x * 64, n0 = blockIdx.y * 64;
  const int x = threadIdx.x, y = threadIdx.y;
#pragma unroll
  for (int j = 0; j < 16; ++j) {
    int e = y * 16 + j;
    tile[e][x] = X[(size_t)(e0 + e) * N_ + n0 + x];
  }
  __syncthreads();
#pragma unroll
  for (int j = 0; j < 16; ++j) {
    int nl = y * 16 + j;
    float v = tile[x][nl];
    f16 h = (f16)v;
    H[(size_t)(n0 + nl) * E_ + e0 + x] = h;
    L[(size_t)(n0 + nl) * E_ + e0 + x] = (f16)(v - (float)h);
  }
}

// ---- projection GEMM (pipelined 2x2-wave 128x128) -----------------------
__global__ __launch_bounds__(256, 2) void k_proj(
    const f16* __restrict__ XqH, const f16* __restrict__ XqL,
    const f16* __restrict__ XkH, const f16* __restrict__ XkL,
    const f16* __restrict__ WqH, const f16* __restrict__ WqL,
    const f16* __restrict__ WkH, const f16* __restrict__ WkL,
    const float* __restrict__ bq, const float* __restrict__ bk,
    f16* __restrict__ QH, f16* __restrict__ QL,
    f16* __restrict__ KH, f16* __restrict__ KL) {
  __shared__ char lds[65536];   // A:[2]x16K @0, B:[2]x16K @32768
  const int b = blockIdx.z >> 1, kind = blockIdx.z & 1;
  const f16* AH = (kind ? XkH : XqH) + (size_t)b * N_ * E_;
  const f16* AL = (kind ? XkL : XqL) + (size_t)b * N_ * E_;
  const f16* BH = kind ? WkH : WqH;
  const f16* BL = kind ? WkL : WqL;
  const float* bias = kind ? bk : bq;
  f16* OH = (kind ? KH : QH) + (size_t)b * N_ * E_;
  f16* OL = (kind ? KL : QL) + (size_t)b * N_ * E_;
  const int n0 = blockIdx.x * 128, f0 = blockIdx.y * 128;
  const int l = threadIdx.x & 63, w = threadIdx.x >> 6;
  const int wr = (w >> 1) * 64, wc = (w & 1) * 64;
  const int r15 = l & 15;

  const int q = (l & 7) ^ (l >> 3);
  const size_t soff = (size_t)(w * 8 + (l >> 3)) * E_ + (q & 3) * 8;
  const f16* sA = (q < 4 ? AH : AL) + (size_t)n0 * E_ + soff;
  const f16* sB = (q < 4 ? BH : BL) + (size_t)f0 * E_ + soff;

  auto STAGE = [&](int k) {
    char* dA = lds + ((k & 1) << 14) + w * 1024;
    char* dB = lds + 32768 + ((k & 1) << 14) + w * 1024;
    const f16* pa = sA + k * 32;
    const f16* pb = sB + k * 32;
#pragma unroll
    for (int c = 0; c < 4; ++c) {
      gll16(pa + (size_t)c * 32 * E_, dA + c * 4096);
      gll16(pb + (size_t)c * 32 * E_, dB + c * 4096);
    }
  };

  const int pH16 = ((l >> 4) ^ (l & 7)) * 16;
  const int aoffH = (wr + r15) * 128 + pH16;
  const int boffH = (wc + r15) * 128 + pH16;

  f32x4 acc[4][4] = {};
  STAGE(0);
#pragma unroll 2
  for (int k = 0; k < 16; ++k) {
    if (k < 15) { STAGE(k + 1); waitv8(); } else { waitv0(); }
    __builtin_amdgcn_sched_barrier(0);
    __builtin_amdgcn_s_barrier();
    const char* cA = lds + ((k & 1) << 14);
    const char* cB = lds + 32768 + ((k & 1) << 14);
    f16x8 ah[4], al[4], bh[4], bl[4];
#pragma unroll
    for (int i = 0; i < 4; ++i) {
      ah[i] = *(const f16x8*)(cA + aoffH + i * 2048);
      al[i] = *(const f16x8*)(cA + (aoffH ^ 64) + i * 2048);
      bh[i] = *(const f16x8*)(cB + boffH + i * 2048);
      bl[i] = *(const f16x8*)(cB + (boffH ^ 64) + i * 2048);
    }
    __builtin_amdgcn_s_setprio(1);
#pragma unroll
    for (int i = 0; i < 4; ++i)
#pragma unroll
      for (int j = 0; j < 4; ++j) {
        acc[i][j] = mfma16(ah[i], bh[j], acc[i][j]);
        acc[i][j] = mfma16(ah[i], bl[j], acc[i][j]);
        acc[i][j] = mfma16(al[i], bh[j], acc[i][j]);
      }
    __builtin_amdgcn_s_setprio(0);
    __builtin_amdgcn_s_barrier();
  }

  const int rowg = (l >> 4) * 4;
#pragma unroll
  for (int j = 0; j < 4; ++j) {
    int f = f0 + wc + j * 16 + r15;
    float bv = bias[f];
#pragma unroll
    for (int i = 0; i < 4; ++i) {
#pragma unroll
      for (int r = 0; r < 4; ++r) {
        int n = n0 + wr + i * 16 + rowg + r;
        float qv = acc[i][j][r] * (1.0f / WSCALE) + bv;
        f16 h = (f16)qv;
        OH[(size_t)n * E_ + f] = h;
        OL[(size_t)n * E_ + f] = (f16)(qv - (float)h);
      }
    }
  }
}

// ---- kk[b*M+m] = sum_f k^2 ----------------------------------------------
__global__ void k_kk(const f16* __restrict__ KH, const f16* __restrict__ KL,
                     float* __restrict__ kk) {
  int row = blockIdx.x * 4 + (threadIdx.x >> 6);
  int lane = threadIdx.x & 63;
  f16x8 h8 = *(const f16x8*)(KH + (size_t)row * E_ + lane * 8);
  f16x8 l8 = *(const f16x8*)(KL + (size_t)row * E_ + lane * 8);
  float s = 0.f;
#pragma unroll
  for (int i = 0; i < 8; ++i) {
    float v = (float)h8[i] + (float)l8[i];
    s += v * v;
  }
#pragma unroll
  for (int o = 32; o; o >>= 1) s += __shfl_xor(s, o);
  if (lane == 0) kk[row] = s;
}

// ---- flash: pipelined S GEMM + online softmax + PV over one m-chunk -----
// grid (N/128, MCH, B); 4x1 waves, 64 flat K-steps (4 m-tiles x 16).
__global__ __launch_bounds__(256, 2) void k_flash(
    const f16* __restrict__ QH, const f16* __restrict__ QL,
    const f16* __restrict__ KH, const f16* __restrict__ KL,
    const float* __restrict__ kk, const float* __restrict__ tgt,
    float* __restrict__ part) {
  __shared__ char lds[73728];   // A:[2]x16K @0, B:[2]x16K @32768, kks @65536, tgs @67584
  float* kks = (float*)(lds + 65536);
  float* tgs = (float*)(lds + 67584);
  const int b = blockIdx.z;
  const int n0 = blockIdx.x * 128;
  const int mc = blockIdx.y, m0c = mc * 512;
  const int tid = threadIdx.x, l = tid & 63, w = tid >> 6;
  const int r15 = l & 15;

  for (int i = tid; i < 512; i += 256) kks[i] = kk[(size_t)b * M_ + m0c + i];
  for (int i = tid; i < 1536; i += 256) {
    int d = i >> 9, m = i & 511;
    tgs[i] = tgt[((size_t)b * 3 + d) * M_ + m0c + m];
  }

  const f16* AH = QH + ((size_t)b * N_ + n0) * E_;
  const f16* AL = QL + ((size_t)b * N_ + n0) * E_;
  const f16* BHb = KH + ((size_t)b * M_ + m0c) * E_;
  const f16* BLb = KL + ((size_t)b * M_ + m0c) * E_;

  const int q = (l & 7) ^ (l >> 3);
  const size_t soff = (size_t)(w * 8 + (l >> 3)) * E_ + (q & 3) * 8;
  const f16* sA = (q < 4 ? AH : AL) + soff;
  const f16* sB = (q < 4 ? BHb : BLb) + soff;

  auto STAGE = [&](int s) {
    int mt_ = s >> 4, k_ = s & 15;
    char* dA = lds + ((s & 1) << 14) + w * 1024;
    char* dB = lds + 32768 + ((s & 1) << 14) + w * 1024;
    const f16* pa = sA + k_ * 32;
    const f16* pb = sB + (size_t)mt_ * 128 * E_ + k_ * 32;
#pragma unroll
    for (int c = 0; c < 4; ++c) {
      gll16(pa + (size_t)c * 32 * E_, dA + c * 4096);
      gll16(pb + (size_t)c * 32 * E_, dB + c * 4096);
    }
  };

  const int pH16 = ((l >> 4) ^ (l & 7)) * 16;
  const int aoffH = (w * 32 + r15) * 128 + pH16;
  const int boffH = r15 * 128 + pH16;

  float mrun[8], psum[8], pp0[8], pp1[8], pp2[8];
#pragma unroll
  for (int x = 0; x < 8; ++x) {
    mrun[x] = -3.0e38f; psum[x] = 0.f; pp0[x] = 0.f; pp1[x] = 0.f; pp2[x] = 0.f;
  }

  STAGE(0);
  for (int mt = 0; mt < 4; ++mt) {
    f32x4 acc[2][8] = {};
#pragma unroll 2
    for (int k = 0; k < 16; ++k) {
      const int s = mt * 16 + k;
      if (s < 63) { STAGE(s + 1); waitv8(); } else { waitv0(); }
      __builtin_amdgcn_sched_barrier(0);
      __builtin_amdgcn_s_barrier();
      const char* cA = lds + ((s & 1) << 14);
      const char* cB = lds + 32768 + ((s & 1) << 14);
      f16x8 ah0 = *(const f16x8*)(cA + aoffH);
      f16x8 ah1 = *(const f16x8*)(cA + aoffH + 2048);
      f16x8 al0 = *(const f16x8*)(cA + (aoffH ^ 64));
      f16x8 al1 = *(const f16x8*)(cA + (aoffH ^ 64) + 2048);
      __builtin_amdgcn_s_setprio(1);
#pragma unroll
      for (int j = 0; j < 8; ++j) {
        f16x8 bh = *(const f16x8*)(cB + boffH + j * 2048);
        f16x8 bl = *(const f16x8*)(cB + (boffH ^ 64) + j * 2048);
        acc[0][j] = mfma16(ah0, bh, acc[0][j]);
        acc[1][j] = mfma16(ah1, bh, acc[1][j]);
        acc[0][j] = mfma16(ah0, bl, acc[0][j]);
        acc[1][j] = mfma16(ah1, bl, acc[1][j]);
        acc[0][j] = mfma16(al0, bh, acc[0][j]);
        acc[1][j] = mfma16(al1, bh, acc[1][j]);
      }
      __builtin_amdgcn_s_setprio(0);
      __builtin_amdgcn_s_barrier();
    }

    // online softmax update for this m-tile (stage of next tile in flight)
    float kv[8], tv0[8], tv1[8], tv2[8];
#pragma unroll
    for (int j = 0; j < 8; ++j) {
      int ml = mt * 128 + j * 16 + r15;
      kv[j] = kks[ml];
      tv0[j] = tgs[ml];
      tv1[j] = tgs[512 + ml];
      tv2[j] = tgs[1024 + ml];
    }
#pragma unroll
    for (int i = 0; i < 2; ++i) {
#pragma unroll
      for (int r = 0; r < 4; ++r) {
        const int x = i * 4 + r;
        float s[8];
        float rmax = -3.0e38f;
#pragma unroll
        for (int j = 0; j < 8; ++j) {
          s[j] = 2.0f * acc[i][j][r] - kv[j];
          rmax = fmaxf(rmax, s[j]);
        }
        rmax = fmaxf(rmax, __shfl_xor(rmax, 1));
        rmax = fmaxf(rmax, __shfl_xor(rmax, 2));
        rmax = fmaxf(rmax, __shfl_xor(rmax, 4));
        rmax = fmaxf(rmax, __shfl_xor(rmax, 8));
        float nm = fmaxf(mrun[x], rmax);
        float sc = __expf(mrun[x] - nm);
        mrun[x] = nm;
        psum[x] *= sc; pp0[x] *= sc; pp1[x] *= sc; pp2[x] *= sc;
#pragma unroll
        for (int j = 0; j < 8; ++j) {
          float e = __expf(s[j] - nm);
          psum[x] += e;
          pp0[x] += e * tv0[j];
          pp1[x] += e * tv1[j];
          pp2[x] += e * tv2[j];
        }
      }
    }
  }

#pragma unroll
  for (int x = 0; x < 8; ++x) {
#pragma unroll
    for (int o = 1; o <= 8; o <<= 1) {
      psum[x] += __shfl_xor(psum[x], o);
      pp0[x] += __shfl_xor(pp0[x], o);
      pp1[x] += __shfl_xor(pp1[x], o);
      pp2[x] += __shfl_xor(pp2[x], o);
    }
  }
  if (r15 == 0) {
    const int hi = l >> 4;
#pragma unroll
    for (int x = 0; x < 8; ++x) {
      int i = x >> 2, r = x & 3;
      int n = n0 + w * 32 + i * 16 + hi * 4 + r;
      size_t pb = ((size_t)(b * N_ + n) * MCH + mc) * 5;
      part[pb + 0] = mrun[x];
      part[pb + 1] = psum[x];
      part[pb + 2] = pp0[x];
      part[pb + 3] = pp1[x];
      part[pb + 4] = pp2[x];
    }
  }
}

// ---- combine per-chunk partials -> output -------------------------------
__global__ void k_comb(const float* __restrict__ part, float* __restrict__ out) {
  int idx = blockIdx.x * 256 + threadIdx.x;     // b*N + n
  int b = idx >> 12, n = idx & (N_ - 1);
  const float* p = part + (size_t)idx * MCH * 5;
  float M = -3.0e38f;
#pragma unroll
  for (int c = 0; c < MCH; ++c) M = fmaxf(M, p[c * 5]);
  float S = 0.f, P0 = 0.f, P1 = 0.f, P2 = 0.f;
#pragma unroll
  for (int c = 0; c < MCH; ++c) {
    float e = __expf(p[c * 5] - M);
    S += p[c * 5 + 1] * e;
    P0 += p[c * 5 + 2] * e;
    P1 += p[c * 5 + 3] * e;
    P2 += p[c * 5 + 4] * e;
  }
  float inv = 1.0f / S;
  float* oc = out + (size_t)B_ * 3 * N_;
  oc[((size_t)b * 3 + 0) * N_ + n] = P0 * inv;
  oc[((size_t)b * 3 + 1) * N_ + n] = P1 * inv;
  oc[((size_t)b * 3 + 2) * N_ + n] = P2 * inv;
}

// ---- src passthrough ----------------------------------------------------
__global__ void k_copy(const float* __restrict__ src, float* __restrict__ out) {
  int i = blockIdx.x * 256 + threadIdx.x;
  out[i] = src[i];
}

extern "C" void kernel_launch(void* const* d_in, const int* in_sizes, int n_in,
                              void* d_out, int out_size, void* d_ws, size_t ws_size,
                              hipStream_t stream) {
  const float* src_emb = (const float*)d_in[0];
  const float* tgt_emb = (const float*)d_in[1];
  const float* src     = (const float*)d_in[2];
  const float* tgt     = (const float*)d_in[3];
  const float* Wq      = (const float*)d_in[4];
  const float* bq      = (const float*)d_in[5];
  const float* Wk      = (const float*)d_in[6];
  const float* bk      = (const float*)d_in[7];
  float* out = (float*)d_out;

  constexpr size_t SZX = (size_t)B_ * N_ * E_;
  constexpr size_t OFFW = 4 * SZX * sizeof(f16);
  constexpr size_t OFFQ = OFFW + 4 * (size_t)E_ * E_ * sizeof(f16);
  constexpr size_t OFFK2 = OFFQ + 4 * SZX * sizeof(f16);
  constexpr size_t OFFP = OFFK2 + (size_t)B_ * M_ * sizeof(float);
  constexpr size_t NEED = OFFP + (size_t)B_ * N_ * MCH * 5 * sizeof(float);
  if (ws_size < NEED) return;

  char* ws = (char*)d_ws;
  f16* XqH = (f16*)(ws);
  f16* XqL = XqH + SZX;
  f16* XkH = XqL + SZX;
  f16* XkL = XkH + SZX;
  f16* WqH = (f16*)(ws + OFFW);
  f16* WqL = WqH + (size_t)E_ * E_;
  f16* WkH = WqL + (size_t)E_ * E_;
  f16* WkL = WkH + (size_t)E_ * E_;
  f16* QH = (f16*)(ws + OFFQ);
  f16* QL = QH + SZX;
  f16* KH = QL + SZX;
  f16* KL = KH + SZX;
  float* kk = (float*)(ws + OFFK2);
  float* part = (float*)(ws + OFFP);

  k_split_w<<<dim3(E_ * E_ / 256), 256, 0, stream>>>(Wq, Wk, WqH, WqL, WkH, WkL);
  k_tsplit<<<dim3(E_ / 64, N_ / 64, B_ * 2), dim3(64, 4), 0, stream>>>(
      src_emb, tgt_emb, XqH, XqL, XkH, XkL);
  k_proj<<<dim3(N_ / 128, E_ / 128, B_ * 2), 256, 0, stream>>>(
      XqH, XqL, XkH, XkL, WqH, WqL, WkH, WkL, bq, bk, QH, QL, KH, KL);
  k_kk<<<dim3(B_ * M_ / 4), 256, 0, stream>>>(KH, KL, kk);
  k_flash<<<dim3(N_ / 128, MCH, B_), 256, 0, stream>>>(QH, QL, KH, KL, kk, tgt, part);
  k_comb<<<dim3(B_ * N_ / 256), 256, 0, stream>>>(part, out);
  k_copy<<<dim3(B_ * 3 * N_ / 256), 256, 0, stream>>>(src, out);
}